// Round 1
// baseline (233.264 us; speedup 1.0000x reference)
//
#include <hip/hip_runtime.h>
#include <stdint.h>

#define K_DIM 4096
#define N_DIM 11008
#define NCOL  1376   // N/8

typedef __attribute__((ext_vector_type(4))) float  f32x4;
typedef __attribute__((ext_vector_type(8))) __bf16 bf16x8;
typedef __attribute__((ext_vector_type(4))) __bf16 bf16x4;

__device__ __forceinline__ void gload_lds16(const void* g, void* l) {
  __builtin_amdgcn_global_load_lds((const __attribute__((address_space(1))) void*)g,
                                   (__attribute__((address_space(3))) void*)l,
                                   16, 0, 0);
}

// ---------- prologue 1: x fp32 -> bf16 ----------
__global__ void __launch_bounds__(256) convert_x_kernel(const float* __restrict__ x,
                                                        __bf16* __restrict__ a) {
  size_t i = ((size_t)blockIdx.x * 256u + threadIdx.x) * 8u;
  f32x4 v0 = *(const f32x4*)(x + i);
  f32x4 v1 = *(const f32x4*)(x + i + 4);
  bf16x8 o;
  o[0] = (__bf16)v0[0]; o[1] = (__bf16)v0[1]; o[2] = (__bf16)v0[2]; o[3] = (__bf16)v0[3];
  o[4] = (__bf16)v1[0]; o[5] = (__bf16)v1[1]; o[6] = (__bf16)v1[2]; o[7] = (__bf16)v1[3];
  *(bf16x8*)(a + i) = o;
}

// ---------- prologue 2: AWQ dequant -> Wt bf16 [N][K] (transposed via LDS) ----------
__global__ void __launch_bounds__(256) dequant_kernel(const int* __restrict__ qw,
                                                      const int* __restrict__ qz,
                                                      const float* __restrict__ sc,
                                                      __bf16* __restrict__ wt) {
  constexpr int SH[8] = {0, 16, 4, 20, 8, 24, 12, 28};  // AWQ [0,4,1,5,2,6,3,7]*4
  __shared__ __bf16 tile[64][72];  // [n_local][k_local], pad 72 (144B = 9*16B, keeps 16B align)
  const int bid = blockIdx.x;
  const int tk = bid & 63;   // K/64 = 64 tiles
  const int tn = bid >> 6;   // N/64 = 172 tiles
  const int k0 = tk * 64;
  const int c0 = tn * 8;
  const int t = threadIdx.x;
#pragma unroll
  for (int r = 0; r < 2; ++r) {
    int idx = r * 256 + t;
    int kk = idx >> 3;          // 0..63
    int cc = idx & 7;           // 0..7
    int k = k0 + kk;
    int c = c0 + cc;
    uint32_t q  = (uint32_t)qw[(size_t)k * NCOL + c];
    int g = k >> 7;             // k / 128
    uint32_t zq = (uint32_t)qz[(size_t)g * NCOL + c];
    const float* s = sc + (size_t)g * N_DIM + (size_t)c * 8;
#pragma unroll
    for (int j = 0; j < 8; ++j) {
      int wv = (int)((q >> SH[j]) & 15u) - (int)((zq >> SH[j]) & 15u);
      tile[cc * 8 + j][kk] = (__bf16)((float)wv * s[j]);
    }
  }
  __syncthreads();
  const int n0 = tn * 64;
#pragma unroll
  for (int r = 0; r < 2; ++r) {
    int idx = r * 256 + t;
    int row = idx >> 3;         // 0..63
    int kc = idx & 7;           // 0..7
    bf16x8 v = *(const bf16x8*)&tile[row][kc * 8];
    *(bf16x8*)(wt + (size_t)(n0 + row) * K_DIM + k0 + kc * 8) = v;
  }
}

// ---------- main GEMM: out[M][N] = x @ W + bias ----------
// 128x128 tile, BK=64, 4 waves each 64x64 (4x4 frags of 16x16x32 bf16 MFMA).
// LDS tiles As/Bs: [row 0..127][64 bf16 = 8 granules of 16B], granule g XOR-swizzled
// with (row&7). Direct path: linear LDS dest (global_load_lds) + inverse-swizzled
// global source. Fused path: swizzle applied on ds_write side.
template <bool FUSED>
__global__ void __launch_bounds__(256, 2) wq_gemm_kernel(
    const __bf16* __restrict__ A,    // [M][K] bf16 (ws), !FUSED
    const __bf16* __restrict__ Wt,   // [N][K] bf16 (ws), !FUSED
    const float* __restrict__ Xf,    // [M][K] fp32, FUSED
    const int* __restrict__ qw,
    const int* __restrict__ qz,
    const float* __restrict__ sc,
    const float* __restrict__ bias,
    float* __restrict__ out,
    const int Mblk)
{
  constexpr int SH[8] = {0, 16, 4, 20, 8, 24, 12, 28};
  __shared__ char As[128 * 128];
  __shared__ char Bs[128 * 128];

  const int nwg = gridDim.x;
  int bid = blockIdx.x;
  if ((nwg & 7) == 0) {                 // XCD-aware swizzle (bijective when nwg%8==0)
    const int cpx = nwg >> 3;
    bid = (bid & 7) * cpx + (bid >> 3);
  }
  const int bm = bid % Mblk;            // m-fastest: XCD chunk reuses B panels in L2
  const int bn = bid / Mblk;
  const int m0 = bm * 128;
  const int n0 = bn * 128;

  const int t = threadIdx.x;
  const int lane = t & 63;
  const int w = t >> 6;
  const int wr = w >> 1;
  const int wc = w & 1;
  const int lrow = lane & 15;
  const int lk = lane >> 4;

  f32x4 zero = {0.f, 0.f, 0.f, 0.f};
  f32x4 acc[4][4];
#pragma unroll
  for (int i = 0; i < 4; ++i)
#pragma unroll
    for (int j = 0; j < 4; ++j) acc[i][j] = zero;

  for (int kt = 0; kt < K_DIM / 64; ++kt) {
    const int k0 = kt * 64;
    __syncthreads();
    if constexpr (!FUSED) {
#pragma unroll
      for (int i = 0; i < 4; ++i) {
        const int cid = i * 256 + t;
        const int rp = cid >> 3;                 // physical row 0..127
        const int gl = (cid & 7) ^ (rp & 7);     // inverse-swizzled source granule
        gload_lds16(A  + (size_t)(m0 + rp) * K_DIM + k0 + gl * 8, As + i * 4096 + w * 1024);
        gload_lds16(Wt + (size_t)(n0 + rp) * K_DIM + k0 + gl * 8, Bs + i * 4096 + w * 1024);
      }
    } else {
      {  // A: fp32 -> bf16, reg-staged, swizzled ds_write
        const int row = t >> 1;
        const int half = t & 1;
        const float* src = Xf + (size_t)(m0 + row) * K_DIM + k0 + half * 32;
#pragma unroll
        for (int gg = 0; gg < 4; ++gg) {
          f32x4 u0 = *(const f32x4*)(src + gg * 8);
          f32x4 u1 = *(const f32x4*)(src + gg * 8 + 4);
          bf16x8 o;
          o[0] = (__bf16)u0[0]; o[1] = (__bf16)u0[1]; o[2] = (__bf16)u0[2]; o[3] = (__bf16)u0[3];
          o[4] = (__bf16)u1[0]; o[5] = (__bf16)u1[1]; o[6] = (__bf16)u1[2]; o[7] = (__bf16)u1[3];
          const int g = (half * 4 + gg) ^ (row & 7);
          *(bf16x8*)(As + row * 128 + (g << 4)) = o;
        }
      }
      {  // B: dequant 4 k-rows x 1 col-block per thread, swizzled ds_write
        const int cc = t & 15;
        const int kq = t >> 4;
        const int c = bn * 16 + cc;
        const int kb = k0 + kq * 4;
        const int grp = kb >> 7;      // group constant within BK=64 (64-aligned)
        const uint32_t zq = (uint32_t)qz[(size_t)grp * NCOL + c];
        const float* s = sc + (size_t)grp * N_DIM + (size_t)c * 8;
        const uint32_t q0 = (uint32_t)qw[(size_t)(kb + 0) * NCOL + c];
        const uint32_t q1 = (uint32_t)qw[(size_t)(kb + 1) * NCOL + c];
        const uint32_t q2 = (uint32_t)qw[(size_t)(kb + 2) * NCOL + c];
        const uint32_t q3 = (uint32_t)qw[(size_t)(kb + 3) * NCOL + c];
        const int gq = kq >> 1;            // all 4 k land in one 16B granule
        const int sub = (kq & 1) * 8;      // byte offset within granule
#pragma unroll
        for (int j = 0; j < 8; ++j) {
          const int z = (int)((zq >> SH[j]) & 15u);
          const float sj = s[j];
          bf16x4 v;
          v[0] = (__bf16)((float)((int)((q0 >> SH[j]) & 15u) - z) * sj);
          v[1] = (__bf16)((float)((int)((q1 >> SH[j]) & 15u) - z) * sj);
          v[2] = (__bf16)((float)((int)((q2 >> SH[j]) & 15u) - z) * sj);
          v[3] = (__bf16)((float)((int)((q3 >> SH[j]) & 15u) - z) * sj);
          const int row = cc * 8 + j;
          const int gp = gq ^ (row & 7);
          *(bf16x4*)(Bs + row * 128 + (gp << 4) + sub) = v;
        }
      }
    }
    __syncthreads();
#pragma unroll
    for (int kk = 0; kk < 2; ++kk) {
      bf16x8 av[4], bv[4];
#pragma unroll
      for (int m = 0; m < 4; ++m) {
        const int row = wr * 64 + m * 16 + lrow;
        const int g = (kk * 4 + lk) ^ (row & 7);
        av[m] = *(const bf16x8*)(As + row * 128 + (g << 4));
      }
#pragma unroll
      for (int n = 0; n < 4; ++n) {
        const int row = wc * 64 + n * 16 + lrow;
        const int g = (kk * 4 + lk) ^ (row & 7);
        bv[n] = *(const bf16x8*)(Bs + row * 128 + (g << 4));
      }
#pragma unroll
      for (int m = 0; m < 4; ++m)
#pragma unroll
        for (int n = 0; n < 4; ++n)
          acc[m][n] = __builtin_amdgcn_mfma_f32_16x16x32_bf16(av[m], bv[n], acc[m][n], 0, 0, 0);
    }
  }

  // epilogue: C/D layout col=lane&15, row=(lane>>4)*4+reg (m89-verified)
  const int orow0 = m0 + wr * 64;
  const int ocol0 = n0 + wc * 64;
#pragma unroll
  for (int n = 0; n < 4; ++n) {
    const int col = ocol0 + n * 16 + lrow;
    const float bvl = bias[col];
#pragma unroll
    for (int m = 0; m < 4; ++m) {
      const int r0 = orow0 + m * 16 + lk * 4;
      float* po = out + (size_t)r0 * N_DIM + col;
      po[0]               = acc[m][n][0] + bvl;
      po[(size_t)N_DIM]   = acc[m][n][1] + bvl;
      po[2 * (size_t)N_DIM] = acc[m][n][2] + bvl;
      po[3 * (size_t)N_DIM] = acc[m][n][3] + bvl;
    }
  }
}

extern "C" void kernel_launch(void* const* d_in, const int* in_sizes, int n_in,
                              void* d_out, int out_size, void* d_ws, size_t ws_size,
                              hipStream_t stream) {
  const float* x    = (const float*)d_in[0];
  const int* qw     = (const int*)d_in[1];
  const int* qz     = (const int*)d_in[2];
  const float* sc   = (const float*)d_in[3];
  const float* bias = (const float*)d_in[4];
  float* out = (float*)d_out;

  const int M = in_sizes[0] / K_DIM;        // 2048
  const int Mblk = M / 128;                 // 16
  const int grid = Mblk * (N_DIM / 128);    // 1376

  const size_t abytes = (size_t)M * K_DIM * 2;       // A bf16
  const size_t wbytes = (size_t)N_DIM * K_DIM * 2;   // Wt bf16

  if (ws_size >= abytes + wbytes) {
    __bf16* Aw = (__bf16*)d_ws;
    __bf16* Wt = (__bf16*)((char*)d_ws + abytes);
    convert_x_kernel<<<(M * K_DIM) / (256 * 8), 256, 0, stream>>>(x, Aw);
    dequant_kernel<<<(K_DIM / 64) * (N_DIM / 64), 256, 0, stream>>>(qw, qz, sc, Wt);
    wq_gemm_kernel<false><<<grid, 256, 0, stream>>>(Aw, Wt, nullptr, nullptr, nullptr,
                                                    nullptr, bias, out, Mblk);
  } else {
    wq_gemm_kernel<true><<<grid, 256, 0, stream>>>(nullptr, nullptr, x, qw, qz, sc,
                                                   bias, out, Mblk);
  }
}